// Round 1
// baseline (762.120 us; speedup 1.0000x reference)
//
#include <hip/hip_runtime.h>

typedef __attribute__((ext_vector_type(4))) float f32x4;
typedef __attribute__((ext_vector_type(8))) short short8;
typedef unsigned short ushort_t;
typedef unsigned int uint_t;

#define B_  256
#define T_  128
#define R_  32768       // B*T rows
#define E_  192         // embed
#define F_  768         // 4*embed
#define V_  96          // vocab
#define L_  6
#define EPS_ 1e-5f

__device__ __forceinline__ float bf2f(ushort_t u) {
    uint_t i = ((uint_t)u) << 16;
    return __builtin_bit_cast(float, i);
}
__device__ __forceinline__ ushort_t f2bf(float f) {
    uint_t i = __builtin_bit_cast(uint_t, f);
    uint_t r = (i + 0x7fffu + ((i >> 16) & 1u)) >> 16;   // RNE
    return (ushort_t)r;
}

// ---------------- weight convert + transpose (f32 -> bf16, k-minor) ----------------
// W1 [L][192][768] -> w1t [L][768][192]; W2 [L][768][192] -> w2t [L][192][768];
// Wf [192][96] -> wft [96][192]
__global__ void wconv_k(const float* __restrict__ W1, const float* __restrict__ W2,
                        const float* __restrict__ Wf,
                        ushort_t* __restrict__ w1t, ushort_t* __restrict__ w2t,
                        ushort_t* __restrict__ wft)
{
    int i = blockIdx.x * 256 + threadIdx.x;
    const int NW = L_ * E_ * F_;                 // 884736
    if (i < NW) {
        int l = i / (E_ * F_), rem = i % (E_ * F_);
        int k = rem / F_, n = rem % F_;
        w1t[((size_t)l * F_ + n) * E_ + k] = f2bf(W1[i]);
        return;
    }
    i -= NW;
    if (i < NW) {
        int l = i / (F_ * E_), rem = i % (F_ * E_);
        int k = rem / E_, n = rem % E_;
        w2t[((size_t)l * E_ + n) * F_ + k] = f2bf(W2[i]);
        return;
    }
    i -= NW;
    if (i < E_ * V_) {
        int k = i / V_, n = i % V_;
        wft[(size_t)n * E_ + k] = f2bf(Wf[i]);
    }
}

// ---------------- embedding: x = tok_emb[index] + pos_emb[t]  (bf16 out) ----------------
__global__ void embed_k(const int* __restrict__ idx, const float* __restrict__ tok,
                        const float* __restrict__ pos, ushort_t* __restrict__ x)
{
    int t = blockIdx.x * 256 + threadIdx.x;      // over R_*48, 4 elems each
    if (t >= R_ * (E_ / 4)) return;
    int r = t / (E_ / 4), c = (t % (E_ / 4)) * 4;
    int id = idx[r], p = r & (T_ - 1);
    float4 a = *(const float4*)(tok + (size_t)id * E_ + c);
    float4 b = *(const float4*)(pos + (size_t)p * E_ + c);
    uint2 o;
    o.x = (uint_t)f2bf(a.x + b.x) | ((uint_t)f2bf(a.y + b.y) << 16);
    o.y = (uint_t)f2bf(a.z + b.z) | ((uint_t)f2bf(a.w + b.w) << 16);
    *(uint2*)(x + (size_t)r * E_ + c) = o;
}

// ---------------- LayerNorm (optionally applied twice): out = LN2(LN1(x)) ----------------
// wave handles 4 rows; 16 lanes per row; 12 elems per lane
__global__ __launch_bounds__(256) void ln_k(const ushort_t* __restrict__ xin,
    const float* __restrict__ g1, const float* __restrict__ b1,
    const float* __restrict__ g2, const float* __restrict__ b2,
    ushort_t* __restrict__ out, int two)
{
    const int tid = threadIdx.x, lane = tid & 63, w = tid >> 6;
    const int lr = lane & 15, sub = lane >> 4;
    const int row = blockIdx.x * 16 + w * 4 + sub;
    const ushort_t* src = xin + (size_t)row * E_ + lr * 12;
    uint2 p0 = *(const uint2*)(src);
    uint2 p1 = *(const uint2*)(src + 4);
    uint2 p2 = *(const uint2*)(src + 8);
    uint_t pw[6] = {p0.x, p0.y, p1.x, p1.y, p2.x, p2.y};
    float v[12];
#pragma unroll
    for (int j = 0; j < 6; ++j) {
        v[2 * j]     = bf2f((ushort_t)pw[j]);
        v[2 * j + 1] = bf2f((ushort_t)(pw[j] >> 16));
    }
    float s = 0.f, sq = 0.f;
#pragma unroll
    for (int j = 0; j < 12; ++j) { s += v[j]; sq += v[j] * v[j]; }
#pragma unroll
    for (int m = 1; m < 16; m <<= 1) { s += __shfl_xor(s, m); sq += __shfl_xor(sq, m); }
    float mu = s * (1.f / E_), var = sq * (1.f / E_) - mu * mu;
    float r1 = rsqrtf(var + EPS_);
#pragma unroll
    for (int j = 0; j < 12; ++j) { int c = lr * 12 + j; v[j] = (v[j] - mu) * r1 * g1[c] + b1[c]; }
    if (two) {
        s = 0.f; sq = 0.f;
#pragma unroll
        for (int j = 0; j < 12; ++j) { s += v[j]; sq += v[j] * v[j]; }
#pragma unroll
        for (int m = 1; m < 16; m <<= 1) { s += __shfl_xor(s, m); sq += __shfl_xor(sq, m); }
        mu = s * (1.f / E_); var = sq * (1.f / E_) - mu * mu;
        float r2 = rsqrtf(var + EPS_);
#pragma unroll
        for (int j = 0; j < 12; ++j) { int c = lr * 12 + j; v[j] = (v[j] - mu) * r2 * g2[c] + b2[c]; }
    }
    uint_t o[6];
#pragma unroll
    for (int j = 0; j < 6; ++j) o[j] = (uint_t)f2bf(v[2 * j]) | ((uint_t)f2bf(v[2 * j + 1]) << 16);
    ushort_t* dst = out + (size_t)row * E_ + lr * 12;
    *(uint2*)(dst)     = make_uint2(o[0], o[1]);
    *(uint2*)(dst + 4) = make_uint2(o[2], o[3]);
    *(uint2*)(dst + 8) = make_uint2(o[4], o[5]);
}

// A/B fragment (both matrices stored k-minor): lane l -> row base+(l&15), k = kc*32+(l>>4)*8
__device__ __forceinline__ short8 ldfrag(const ushort_t* __restrict__ p, int row, int ld, int ko)
{
    return *(const short8*)(p + (size_t)row * ld + ko);
}

// ---------------- GEMM1: h = relu(n2 @ W1 + b1), h bf16 [R][768] ----------------
// block: 4 waves over M (128 rows); wave: 32 rows x 64 cols; grid (12 ntiles, 256 mtiles)
__global__ __launch_bounds__(256) void gemm1_k(const ushort_t* __restrict__ n2,
    const ushort_t* __restrict__ w1t, const float* __restrict__ b1,
    ushort_t* __restrict__ h)
{
    const int lane = threadIdx.x & 63, w = threadIdx.x >> 6;
    const int lr = lane & 15, lg = lane >> 4;
    const int row0 = blockIdx.y * 128 + w * 32;
    const int col0 = blockIdx.x * 64;
    f32x4 acc[2][4] = {};
#pragma unroll
    for (int kc = 0; kc < 6; ++kc) {
        int ko = kc * 32 + lg * 8;
        short8 a0 = ldfrag(n2, row0 + lr, E_, ko);
        short8 a1 = ldfrag(n2, row0 + 16 + lr, E_, ko);
        short8 b[4];
#pragma unroll
        for (int j = 0; j < 4; ++j) b[j] = ldfrag(w1t, col0 + j * 16 + lr, E_, ko);
#pragma unroll
        for (int j = 0; j < 4; ++j) {
            acc[0][j] = __builtin_amdgcn_mfma_f32_16x16x32_bf16(a0, b[j], acc[0][j], 0, 0, 0);
            acc[1][j] = __builtin_amdgcn_mfma_f32_16x16x32_bf16(a1, b[j], acc[1][j], 0, 0, 0);
        }
    }
#pragma unroll
    for (int i = 0; i < 2; ++i)
#pragma unroll
        for (int j = 0; j < 4; ++j) {
            int col = col0 + j * 16 + lr;
            float bias = b1[col];
#pragma unroll
            for (int r = 0; r < 4; ++r) {
                int row = row0 + i * 16 + lg * 4 + r;
                float vv = acc[i][j][r] + bias;
                vv = vv > 0.f ? vv : 0.f;
                h[(size_t)row * F_ + col] = f2bf(vv);
            }
        }
}

// ---------------- GEMM2: x = h @ W2 + b2, bf16 [R][192] ----------------
// wave: 32 rows x 96 cols; grid (2 ntiles, 256 mtiles)
__global__ __launch_bounds__(256) void gemm2_k(const ushort_t* __restrict__ h,
    const ushort_t* __restrict__ w2t, const float* __restrict__ b2,
    ushort_t* __restrict__ x)
{
    const int lane = threadIdx.x & 63, w = threadIdx.x >> 6;
    const int lr = lane & 15, lg = lane >> 4;
    const int row0 = blockIdx.y * 128 + w * 32;
    const int col0 = blockIdx.x * 96;
    f32x4 acc[2][6] = {};
#pragma unroll 4
    for (int kc = 0; kc < 24; ++kc) {
        int ko = kc * 32 + lg * 8;
        short8 a0 = ldfrag(h, row0 + lr, F_, ko);
        short8 a1 = ldfrag(h, row0 + 16 + lr, F_, ko);
#pragma unroll
        for (int j = 0; j < 6; ++j) {
            short8 bb = ldfrag(w2t, col0 + j * 16 + lr, F_, ko);
            acc[0][j] = __builtin_amdgcn_mfma_f32_16x16x32_bf16(a0, bb, acc[0][j], 0, 0, 0);
            acc[1][j] = __builtin_amdgcn_mfma_f32_16x16x32_bf16(a1, bb, acc[1][j], 0, 0, 0);
        }
    }
#pragma unroll
    for (int i = 0; i < 2; ++i)
#pragma unroll
        for (int j = 0; j < 6; ++j) {
            int col = col0 + j * 16 + lr;
            float bias = b2[col];
#pragma unroll
            for (int r = 0; r < 4; ++r) {
                int row = row0 + i * 16 + lg * 4 + r;
                x[(size_t)row * E_ + col] = f2bf(acc[i][j][r] + bias);
            }
        }
}

// ---------------- head: logits = nf @ Wf + bf; write pred f32; loss partials ----------------
__global__ __launch_bounds__(256) void final_k(const ushort_t* __restrict__ nf,
    const ushort_t* __restrict__ wft, const float* __restrict__ bfb,
    const int* __restrict__ tg, float* __restrict__ pred, float* __restrict__ partial)
{
    const int lane = threadIdx.x & 63, w = threadIdx.x >> 6;
    const int lr = lane & 15, lg = lane >> 4;
    const int row0 = blockIdx.x * 128 + w * 32;
    f32x4 acc[2][6] = {};
#pragma unroll
    for (int kc = 0; kc < 6; ++kc) {
        int ko = kc * 32 + lg * 8;
        short8 a0 = ldfrag(nf, row0 + lr, E_, ko);
        short8 a1 = ldfrag(nf, row0 + 16 + lr, E_, ko);
#pragma unroll
        for (int j = 0; j < 6; ++j) {
            short8 bb = ldfrag(wft, j * 16 + lr, E_, ko);
            acc[0][j] = __builtin_amdgcn_mfma_f32_16x16x32_bf16(a0, bb, acc[0][j], 0, 0, 0);
            acc[1][j] = __builtin_amdgcn_mfma_f32_16x16x32_bf16(a1, bb, acc[1][j], 0, 0, 0);
        }
    }
    float lsum = 0.f;
#pragma unroll
    for (int i = 0; i < 2; ++i) {
        float vv[6][4];
#pragma unroll
        for (int j = 0; j < 6; ++j) {
            float bias = bfb[j * 16 + lr];
#pragma unroll
            for (int r = 0; r < 4; ++r) vv[j][r] = acc[i][j][r] + bias;
        }
#pragma unroll
        for (int r = 0; r < 4; ++r) {
            int row = row0 + i * 16 + lg * 4 + r;
            float mx = vv[0][r];
#pragma unroll
            for (int j = 1; j < 6; ++j) mx = fmaxf(mx, vv[j][r]);
#pragma unroll
            for (int m = 1; m < 16; m <<= 1) mx = fmaxf(mx, __shfl_xor(mx, m));
            float se = 0.f;
#pragma unroll
            for (int j = 0; j < 6; ++j) se += expf(vv[j][r] - mx);
#pragma unroll
            for (int m = 1; m < 16; m <<= 1) se += __shfl_xor(se, m);
            int t = tg[row];
#pragma unroll
            for (int j = 0; j < 6; ++j)
                if (((t >> 4) == j) & ((t & 15) == lr)) lsum += mx + logf(se) - vv[j][r];
#pragma unroll
            for (int j = 0; j < 6; ++j) pred[(size_t)row * V_ + j * 16 + lr] = vv[j][r];
        }
    }
#pragma unroll
    for (int m = 1; m < 64; m <<= 1) lsum += __shfl_xor(lsum, m);
    __shared__ float ls[4];
    if (lane == 0) ls[w] = lsum;
    __syncthreads();
    if (threadIdx.x == 0) partial[blockIdx.x] = ls[0] + ls[1] + ls[2] + ls[3];
}

__global__ void lossred_k(const float* __restrict__ partial, float* __restrict__ out)
{
    __shared__ double sd[256];
    int t = threadIdx.x;
    sd[t] = (double)partial[t];
    __syncthreads();
    for (int s = 128; s > 0; s >>= 1) {
        if (t < s) sd[t] += sd[t + s];
        __syncthreads();
    }
    if (t == 0) out[0] = (float)(sd[0] / (double)R_);
}

extern "C" void kernel_launch(void* const* d_in, const int* in_sizes, int n_in,
                              void* d_out, int out_size, void* d_ws, size_t ws_size,
                              hipStream_t stream)
{
    (void)in_sizes; (void)n_in; (void)out_size; (void)ws_size;
    const int*   index   = (const int*)  d_in[0];
    const int*   targets = (const int*)  d_in[1];
    const float* tok     = (const float*)d_in[2];
    const float* pos     = (const float*)d_in[3];
    const float* ln1g    = (const float*)d_in[4];
    const float* ln1b    = (const float*)d_in[5];
    const float* ln2g    = (const float*)d_in[6];
    const float* ln2b    = (const float*)d_in[7];
    // d_in[8..10] = Wq/Wk/Wv: dead code in reference, never read
    const float* W1      = (const float*)d_in[11];
    const float* b1      = (const float*)d_in[12];
    const float* W2      = (const float*)d_in[13];
    const float* b2      = (const float*)d_in[14];
    const float* fng     = (const float*)d_in[15];
    const float* fnb     = (const float*)d_in[16];
    const float* Wf      = (const float*)d_in[17];
    const float* bfv     = (const float*)d_in[18];

    ushort_t* xbuf  = (ushort_t*)d_ws;                    // [R][192] bf16
    ushort_t* n2buf = xbuf  + (size_t)R_ * E_;            // [R][192] bf16
    ushort_t* hbuf  = n2buf + (size_t)R_ * E_;            // [R][768] bf16
    ushort_t* w1t   = hbuf  + (size_t)R_ * F_;            // [L][768][192] bf16
    ushort_t* w2t   = w1t   + (size_t)L_ * F_ * E_;       // [L][192][768] bf16
    ushort_t* wft   = w2t   + (size_t)L_ * E_ * F_;       // [96][192] bf16
    float*    partial = (float*)(wft + (size_t)V_ * E_);  // [256] f32
    float*    pred  = (float*)d_out;
    float*    lossp = pred + (size_t)R_ * V_;

    wconv_k<<<(2 * L_ * E_ * F_ + E_ * V_ + 255) / 256, 256, 0, stream>>>(W1, W2, Wf, w1t, w2t, wft);
    embed_k<<<(R_ * (E_ / 4) + 255) / 256, 256, 0, stream>>>(index, tok, pos, xbuf);
    for (int l = 0; l < L_; ++l) {
        ln_k<<<R_ / 16, 256, 0, stream>>>(xbuf, ln1g + l * E_, ln1b + l * E_,
                                          ln2g + l * E_, ln2b + l * E_, n2buf, 1);
        gemm1_k<<<dim3(F_ / 64, R_ / 128), 256, 0, stream>>>(n2buf, w1t + (size_t)l * F_ * E_,
                                                             b1 + l * F_, hbuf);
        gemm2_k<<<dim3(E_ / 96, R_ / 128), 256, 0, stream>>>(hbuf, w2t + (size_t)l * E_ * F_,
                                                             b2 + l * E_, xbuf);
    }
    ln_k<<<R_ / 16, 256, 0, stream>>>(xbuf, fng, fnb, nullptr, nullptr, n2buf, 0);
    final_k<<<R_ / 128, 256, 0, stream>>>(n2buf, wft, bfv, targets, pred, partial);
    lossred_k<<<1, 256, 0, stream>>>(partial, lossp);
}

// Round 2
// 678.040 us; speedup vs baseline: 1.1240x; 1.1240x over previous
//
#include <hip/hip_runtime.h>

typedef __attribute__((ext_vector_type(4))) float f32x4;
typedef __attribute__((ext_vector_type(8))) short short8;
typedef unsigned short ushort_t;
typedef unsigned int uint_t;

#define R_  32768
#define E_  192
#define F_  768
#define V_  96
#define L_  6
#define EPS_ 1e-5f

// chunk geometry: F split into 24 chunks of 32
#define W1CH 6400     // 32*200 ushorts per w1 chunk (k stride padded 192->200)
#define W2CH 7680     // 192*40 ushorts per w2 chunk (f stride padded 32->40)
#define NCHUNK 24
#define NT (L_ * NCHUNK)   // 144 total chunks

__device__ __forceinline__ float bf2f(ushort_t u) {
    uint_t i = ((uint_t)u) << 16;
    return __builtin_bit_cast(float, i);
}
__device__ __forceinline__ ushort_t f2bf(float f) {
    uint_t i = __builtin_bit_cast(uint_t, f);
    uint_t r = (i + 0x7fffu + ((i >> 16) & 1u)) >> 16;   // RNE
    return (ushort_t)r;
}
__device__ __forceinline__ short8 pack8(const float* v) {
    uint4 u;
    u.x = (uint_t)f2bf(v[0]) | ((uint_t)f2bf(v[1]) << 16);
    u.y = (uint_t)f2bf(v[2]) | ((uint_t)f2bf(v[3]) << 16);
    u.z = (uint_t)f2bf(v[4]) | ((uint_t)f2bf(v[5]) << 16);
    u.w = (uint_t)f2bf(v[6]) | ((uint_t)f2bf(v[7]) << 16);
    return __builtin_bit_cast(short8, u);
}
__device__ __forceinline__ void unpack8(short8 s, float* v) {
    uint4 u = __builtin_bit_cast(uint4, s);
    v[0] = bf2f((ushort_t)u.x); v[1] = bf2f((ushort_t)(u.x >> 16));
    v[2] = bf2f((ushort_t)u.y); v[3] = bf2f((ushort_t)(u.y >> 16));
    v[4] = bf2f((ushort_t)u.z); v[5] = bf2f((ushort_t)(u.z >> 16));
    v[6] = bf2f((ushort_t)u.w); v[7] = bf2f((ushort_t)(u.w >> 16));
}
__device__ __forceinline__ void ldf8(const float* p, float* o) {
    float4 a = *(const float4*)p, b = *(const float4*)(p + 4);
    o[0] = a.x; o[1] = a.y; o[2] = a.z; o[3] = a.w;
    o[4] = b.x; o[5] = b.y; o[6] = b.z; o[7] = b.w;
}

// ---- C-layout pair (two 16-row M-tiles) -> B-fragment exchange ----
// D_t: lane(g=l>>4,c=l&15) holds M = t*16 + g*4 + r  at column c.
// Want: lane holds M = 8g + j (j=0..7) at column c.
// src for j<4: lane ((g&1)*2)*16 + c, tile g>>1, reg j ; j>=4: +16, reg j-4.
__device__ __forceinline__ void exch(f32x4 D0, f32x4 D1, int lane, float* v) {
    const int srcA = ((lane & 16) << 1) + (lane & 15);
    const int srcB = srcA + 16;
    const bool hi = (lane & 32) != 0;
#pragma unroll
    for (int r = 0; r < 4; ++r) {
        float a0 = __shfl(D0[r], srcA);
        float a1 = __shfl(D1[r], srcA);
        float b0 = __shfl(D0[r], srcB);
        float b1 = __shfl(D1[r], srcB);
        v[r]     = hi ? a1 : a0;
        v[4 + r] = hi ? b1 : b0;
    }
}

// ---- double LayerNorm on register fragments; params from LDS ----
// plds layout: [0]g1 [192]b1 [384]g2 [576]b2 [768]bias1(768) [1536]bias2(192)
__device__ __forceinline__ void ln2_frags(short8 (&xf)[2][6], const float* p, int lane) {
    const int g = lane >> 4;
#pragma unroll
    for (int rj = 0; rj < 2; ++rj) {
        float v[48];
#pragma unroll
        for (int kc = 0; kc < 6; ++kc) unpack8(xf[rj][kc], v + kc * 8);
        float s = 0.f, sq = 0.f;
#pragma unroll
        for (int j = 0; j < 48; ++j) { s += v[j]; sq += v[j] * v[j]; }
        s += __shfl_xor(s, 16); sq += __shfl_xor(sq, 16);
        s += __shfl_xor(s, 32); sq += __shfl_xor(sq, 32);
        float mu = s * (1.f / 192.f);
        float r1 = rsqrtf(sq * (1.f / 192.f) - mu * mu + EPS_);
#pragma unroll
        for (int kc = 0; kc < 6; ++kc) {
            float ga[8], ba[8];
            ldf8(p + kc * 32 + g * 8, ga);
            ldf8(p + 192 + kc * 32 + g * 8, ba);
#pragma unroll
            for (int j = 0; j < 8; ++j)
                v[kc * 8 + j] = (v[kc * 8 + j] - mu) * r1 * ga[j] + ba[j];
        }
        s = 0.f; sq = 0.f;
#pragma unroll
        for (int j = 0; j < 48; ++j) { s += v[j]; sq += v[j] * v[j]; }
        s += __shfl_xor(s, 16); sq += __shfl_xor(sq, 16);
        s += __shfl_xor(s, 32); sq += __shfl_xor(sq, 32);
        float mu2 = s * (1.f / 192.f);
        float r2 = rsqrtf(sq * (1.f / 192.f) - mu2 * mu2 + EPS_);
#pragma unroll
        for (int kc = 0; kc < 6; ++kc) {
            float ga[8], ba[8];
            ldf8(p + 384 + kc * 32 + g * 8, ga);
            ldf8(p + 576 + kc * 32 + g * 8, ba);
            float o[8];
#pragma unroll
            for (int j = 0; j < 8; ++j)
                o[j] = (v[kc * 8 + j] - mu2) * r2 * ga[j] + ba[j];
            xf[rj][kc] = pack8(o);
        }
    }
}

// ---- single LayerNorm, params from global ----
__device__ __forceinline__ void ln1_frags(short8 (&xf)[2][6], const float* gg, const float* bb, int lane) {
    const int g = lane >> 4;
#pragma unroll
    for (int rj = 0; rj < 2; ++rj) {
        float v[48];
#pragma unroll
        for (int kc = 0; kc < 6; ++kc) unpack8(xf[rj][kc], v + kc * 8);
        float s = 0.f, sq = 0.f;
#pragma unroll
        for (int j = 0; j < 48; ++j) { s += v[j]; sq += v[j] * v[j]; }
        s += __shfl_xor(s, 16); sq += __shfl_xor(sq, 16);
        s += __shfl_xor(s, 32); sq += __shfl_xor(sq, 32);
        float mu = s * (1.f / 192.f);
        float r1 = rsqrtf(sq * (1.f / 192.f) - mu * mu + EPS_);
#pragma unroll
        for (int kc = 0; kc < 6; ++kc) {
            float ga[8], ba[8];
            ldf8(gg + kc * 32 + g * 8, ga);
            ldf8(bb + kc * 32 + g * 8, ba);
            float o[8];
#pragma unroll
            for (int j = 0; j < 8; ++j)
                o[j] = (v[kc * 8 + j] - mu) * r1 * ga[j] + ba[j];
            xf[rj][kc] = pack8(o);
        }
    }
}

// ---- weight staging: contiguous prelaid chunks, reg round-trip ----
__device__ __forceinline__ void stage_load(const ushort_t* w1s, const ushort_t* w2s, int t, int tid, uint4* sreg) {
    const char* s1 = (const char*)(w1s + (size_t)t * W1CH);
    const char* s2 = (const char*)(w2s + (size_t)t * W2CH);
#pragma unroll
    for (int it = 0; it < 4; ++it) {
        int off = tid * 16 + it * 4096;
        if (off < 12800) sreg[it] = *(const uint4*)(s1 + off);
        if (off < 15360) sreg[4 + it] = *(const uint4*)(s2 + off);
    }
}
__device__ __forceinline__ void stage_write(ushort_t* dst, int tid, const uint4* sreg) {
    char* d = (char*)dst;
#pragma unroll
    for (int it = 0; it < 4; ++it) {
        int off = tid * 16 + it * 4096;
        if (off < 12800) *(uint4*)(d + off) = sreg[it];
        if (off < 15360) *(uint4*)(d + 12800 + off) = sreg[4 + it];
    }
}
__device__ __forceinline__ void param_load(int l, int tid, const float* g1, const float* b1n,
        const float* g2, const float* b2n, const float* b1, const float* b2, uint4* preg) {
#pragma unroll
    for (int it = 0; it < 2; ++it) {
        int f4 = tid + it * 256;
        const float* s = nullptr;
        if (f4 < 48) s = g1 + l * 192 + f4 * 4;
        else if (f4 < 96) s = b1n + l * 192 + (f4 - 48) * 4;
        else if (f4 < 144) s = g2 + l * 192 + (f4 - 96) * 4;
        else if (f4 < 192) s = b2n + l * 192 + (f4 - 144) * 4;
        else if (f4 < 384) s = b1 + l * 768 + (f4 - 192) * 4;
        else if (f4 < 432) s = b2 + l * 192 + (f4 - 384) * 4;
        if (s) preg[it] = *(const uint4*)s;
    }
}
__device__ __forceinline__ void param_write(float* p, int tid, const uint4* preg) {
#pragma unroll
    for (int it = 0; it < 2; ++it) {
        int f4 = tid + it * 256;
        if (f4 < 432) *(uint4*)(p + f4 * 4) = preg[it];
    }
}

// ---------------- weight convert to chunked padded layouts ----------------
__global__ void wconv_k(const float* __restrict__ W1, const float* __restrict__ W2,
                        const float* __restrict__ Wf,
                        ushort_t* __restrict__ w1s, ushort_t* __restrict__ w2s,
                        ushort_t* __restrict__ wft)
{
    int i = blockIdx.x * 256 + threadIdx.x;
    const int NW = L_ * NCHUNK * 32 * 192;     // 884736
    if (i < NW) {
        // w1s[(l,c,fl)][e] = W1[l][e][c*32+fl],  row stride 200
        int e = i % 192; int i2 = i / 192;
        int fl = i2 % 32; int i3 = i2 / 32;
        int cc = i3 % 24; int l = i3 / 24;
        w1s[(size_t)i2 * 200 + e] = f2bf(W1[((size_t)l * 192 + e) * 768 + cc * 32 + fl]);
        return;
    }
    i -= NW;
    if (i < NW) {
        // w2s[(l,c,e)][fl] = W2[l][c*32+fl][e],  row stride 40
        int fl = i % 32; int i2 = i / 32;
        int e = i2 % 192; int i3 = i2 / 192;
        int cc = i3 % 24; int l = i3 / 24;
        w2s[(size_t)i2 * 40 + fl] = f2bf(W2[((size_t)l * 768 + cc * 32 + fl) * 192 + e]);
        return;
    }
    i -= NW;
    if (i < E_ * V_) {
        int k = i / 96, vv = i % 96;
        wft[(size_t)vv * 192 + k] = f2bf(Wf[i]);   // [V][192] k-minor
    }
}

// ---------------- the whole network in one kernel ----------------
__global__ __launch_bounds__(256, 1) void net_k(
    const int* __restrict__ idxp, const int* __restrict__ tgp,
    const float* __restrict__ tok, const float* __restrict__ pos,
    const float* __restrict__ ln1g, const float* __restrict__ ln1b,
    const float* __restrict__ ln2g, const float* __restrict__ ln2b,
    const float* __restrict__ b1g, const float* __restrict__ b2g,
    const float* __restrict__ fng, const float* __restrict__ fnb,
    const float* __restrict__ bfb,
    const ushort_t* __restrict__ w1s, const ushort_t* __restrict__ w2s,
    const ushort_t* __restrict__ wft,
    float* __restrict__ pred, float* __restrict__ partial)
{
    __shared__ __align__(16) ushort_t wlds[2][W1CH + W2CH];
    __shared__ __align__(16) float plds[2][1728];
    __shared__ float lsred[4];

    const int tid = threadIdx.x, lane = tid & 63, w = tid >> 6;
    const int c = lane & 15, g = lane >> 4;
    const int rowbase = blockIdx.x * 128 + w * 32;

    // ---- embedding -> x fragments (B-frag layout: lane c = row, k minor) ----
    short8 xf[2][6];
#pragma unroll
    for (int rj = 0; rj < 2; ++rj) {
        int row = rowbase + rj * 16 + c;
        int id = idxp[row];
        int tt = row & 127;
#pragma unroll
        for (int kc = 0; kc < 6; ++kc) {
            int k = kc * 32 + g * 8;
            float a[8], b[8], v[8];
            ldf8(tok + (size_t)id * 192 + k, a);
            ldf8(pos + (size_t)tt * 192 + k, b);
#pragma unroll
            for (int j = 0; j < 8; ++j) v[j] = a[j] + b[j];
            xf[rj][kc] = pack8(v);
        }
    }

    // ---- prologue: stage chunk 0 weights + layer 0 params ----
    {
        uint4 sreg[8], preg[2];
        stage_load(w1s, w2s, 0, tid, sreg);
        param_load(0, tid, ln1g, ln1b, ln2g, ln2b, b1g, b2g, preg);
        stage_write(&wlds[0][0], tid, sreg);
        param_write(&plds[0][0], tid, preg);
    }
    __syncthreads();

    int cur = 0, pcur = 0;
    for (int l = 0; l < L_; ++l) {
        ln2_frags(xf, &plds[pcur][0], lane);     // n2 = LN2(LN1(x)) in-register

        f32x4 axT[12][2] = {};                    // x accumulator (E x rows), f32
        for (int cc = 0; cc < NCHUNK; ++cc) {
            const int t = l * NCHUNK + cc;
            // issue next-chunk staging loads (hidden under this chunk's MFMA)
            uint4 sreg[8], preg[2];
            const bool doS = (t + 1 < NT);
            const bool doP = (cc == NCHUNK - 1) && (l + 1 < L_);
            if (doS) stage_load(w1s, w2s, t + 1, tid, sreg);
            if (doP) param_load(l + 1, tid, ln1g, ln1b, ln2g, ln2b, b1g, b2g, preg);

            const ushort_t* wb = &wlds[cur][0];
            // gemm1 (swapped): hT[F_loc][row] += W1frag x xfrag
            uint4 wa[12];
#pragma unroll
            for (int kc = 0; kc < 6; ++kc)
#pragma unroll
                for (int fi = 0; fi < 2; ++fi)
                    wa[kc * 2 + fi] = *(const uint4*)((const char*)wb + (fi * 16 + c) * 400 + kc * 64 + g * 16);
            f32x4 ah[2][2] = {};
#pragma unroll
            for (int kc = 0; kc < 6; ++kc) {
                short8 a0 = __builtin_bit_cast(short8, wa[kc * 2]);
                short8 a1 = __builtin_bit_cast(short8, wa[kc * 2 + 1]);
                ah[0][0] = __builtin_amdgcn_mfma_f32_16x16x32_bf16(a0, xf[0][kc], ah[0][0], 0, 0, 0);
                ah[0][1] = __builtin_amdgcn_mfma_f32_16x16x32_bf16(a0, xf[1][kc], ah[0][1], 0, 0, 0);
                ah[1][0] = __builtin_amdgcn_mfma_f32_16x16x32_bf16(a1, xf[0][kc], ah[1][0], 0, 0, 0);
                ah[1][1] = __builtin_amdgcn_mfma_f32_16x16x32_bf16(a1, xf[1][kc], ah[1][1], 0, 0, 0);
            }
            // convert hT tiles -> h B-fragments (+bias, relu)
            short8 hb[2];
#pragma unroll
            for (int rj = 0; rj < 2; ++rj) {
                float v[8], bv[8];
                exch(ah[0][rj], ah[1][rj], lane, v);
                ldf8(&plds[pcur][768 + cc * 32 + g * 8], bv);
#pragma unroll
                for (int j = 0; j < 8; ++j) {
                    float y = v[j] + bv[j];
                    v[j] = y > 0.f ? y : 0.f;
                }
                hb[rj] = pack8(v);
            }
            // gemm2 (swapped): xT[E][row] += W2frag x hfrag
            uint4 w2r[12];
#pragma unroll
            for (int et = 0; et < 12; ++et)
                w2r[et] = *(const uint4*)((const char*)wb + 12800 + (et * 16 + c) * 80 + g * 16);
#pragma unroll
            for (int et = 0; et < 12; ++et) {
                short8 wq = __builtin_bit_cast(short8, w2r[et]);
                axT[et][0] = __builtin_amdgcn_mfma_f32_16x16x32_bf16(wq, hb[0], axT[et][0], 0, 0, 0);
                axT[et][1] = __builtin_amdgcn_mfma_f32_16x16x32_bf16(wq, hb[1], axT[et][1], 0, 0, 0);
            }
            // land staged data, barrier, flip
            if (doS) stage_write(&wlds[cur ^ 1][0], tid, sreg);
            if (doP) param_write(&plds[pcur ^ 1][0], tid, preg);
            __syncthreads();
            cur ^= 1;
        }
        // layer end: xT accumulator (+b2) -> new x B-fragments
#pragma unroll
        for (int e = 0; e < 6; ++e) {
#pragma unroll
            for (int rj = 0; rj < 2; ++rj) {
                float v[8], bv[8];
                exch(axT[2 * e][rj], axT[2 * e + 1][rj], lane, v);
                ldf8(&plds[pcur][1536 + e * 32 + g * 8], bv);
#pragma unroll
                for (int j = 0; j < 8; ++j) v[j] += bv[j];
                xf[rj][e] = pack8(v);
            }
        }
        pcur ^= 1;
    }

    // ---- final LN + head ----
    ln1_frags(xf, fng, fnb, lane);
    f32x4 av[6][2] = {};
#pragma unroll
    for (int kc = 0; kc < 6; ++kc) {
#pragma unroll
        for (int vt = 0; vt < 6; ++vt) {
            short8 wf = *(const short8*)(wft + (size_t)(vt * 16 + c) * 192 + kc * 32 + g * 8);
            av[vt][0] = __builtin_amdgcn_mfma_f32_16x16x32_bf16(wf, xf[0][kc], av[vt][0], 0, 0, 0);
            av[vt][1] = __builtin_amdgcn_mfma_f32_16x16x32_bf16(wf, xf[1][kc], av[vt][1], 0, 0, 0);
        }
    }
    float lsum = 0.f;
#pragma unroll
    for (int rj = 0; rj < 2; ++rj) {
        int row = rowbase + rj * 16 + c;
        float vv[6][4];
#pragma unroll
        for (int vt = 0; vt < 6; ++vt) {
            float4 bb = *(const float4*)(bfb + vt * 16 + g * 4);
            vv[vt][0] = av[vt][rj][0] + bb.x;
            vv[vt][1] = av[vt][rj][1] + bb.y;
            vv[vt][2] = av[vt][rj][2] + bb.z;
            vv[vt][3] = av[vt][rj][3] + bb.w;
        }
        float mx = -1e30f;
#pragma unroll
        for (int vt = 0; vt < 6; ++vt)
#pragma unroll
            for (int r = 0; r < 4; ++r) mx = fmaxf(mx, vv[vt][r]);
        mx = fmaxf(mx, __shfl_xor(mx, 16));
        mx = fmaxf(mx, __shfl_xor(mx, 32));
        float se = 0.f;
#pragma unroll
        for (int vt = 0; vt < 6; ++vt)
#pragma unroll
            for (int r = 0; r < 4; ++r) se += expf(vv[vt][r] - mx);
        se += __shfl_xor(se, 16);
        se += __shfl_xor(se, 32);
        float lse = logf(se) + mx;
        int tgt = tgp[row];
#pragma unroll
        for (int vt = 0; vt < 6; ++vt)
#pragma unroll
            for (int r = 0; r < 4; ++r)
                if (tgt == vt * 16 + g * 4 + r) lsum += lse - vv[vt][r];
#pragma unroll
        for (int vt = 0; vt < 6; ++vt) {
            float4 o;
            o.x = vv[vt][0]; o.y = vv[vt][1]; o.z = vv[vt][2]; o.w = vv[vt][3];
            *(float4*)(pred + (size_t)row * 96 + vt * 16 + g * 4) = o;
        }
    }
#pragma unroll
    for (int m = 1; m < 64; m <<= 1) lsum += __shfl_xor(lsum, m);
    if (lane == 0) lsred[w] = lsum;
    __syncthreads();
    if (tid == 0) partial[blockIdx.x] = lsred[0] + lsred[1] + lsred[2] + lsred[3];
}

__global__ void lossred_k(const float* __restrict__ partial, float* __restrict__ out)
{
    __shared__ double sd[256];
    int t = threadIdx.x;
    sd[t] = (double)partial[t];
    __syncthreads();
    for (int s = 128; s > 0; s >>= 1) {
        if (t < s) sd[t] += sd[t + s];
        __syncthreads();
    }
    if (t == 0) out[0] = (float)(sd[0] / (double)R_);
}

extern "C" void kernel_launch(void* const* d_in, const int* in_sizes, int n_in,
                              void* d_out, int out_size, void* d_ws, size_t ws_size,
                              hipStream_t stream)
{
    (void)in_sizes; (void)n_in; (void)out_size; (void)ws_size;
    const int*   index   = (const int*)  d_in[0];
    const int*   targets = (const int*)  d_in[1];
    const float* tok     = (const float*)d_in[2];
    const float* pos     = (const float*)d_in[3];
    const float* ln1g    = (const float*)d_in[4];
    const float* ln1b    = (const float*)d_in[5];
    const float* ln2g    = (const float*)d_in[6];
    const float* ln2b    = (const float*)d_in[7];
    // d_in[8..10] = Wq/Wk/Wv: dead in the reference forward
    const float* W1      = (const float*)d_in[11];
    const float* b1      = (const float*)d_in[12];
    const float* W2      = (const float*)d_in[13];
    const float* b2      = (const float*)d_in[14];
    const float* fng     = (const float*)d_in[15];
    const float* fnb     = (const float*)d_in[16];
    const float* Wf      = (const float*)d_in[17];
    const float* bfv     = (const float*)d_in[18];

    ushort_t* w1s = (ushort_t*)d_ws;                        // [144][6400]
    ushort_t* w2s = w1s + (size_t)NT * W1CH;                // [144][7680]
    ushort_t* wft = w2s + (size_t)NT * W2CH;                // [96][192]
    float* partial = (float*)(wft + (size_t)V_ * E_);       // [256]
    float* pred  = (float*)d_out;
    float* lossp = pred + (size_t)R_ * V_;

    const int nconv = 2 * L_ * NCHUNK * 32 * 192 + E_ * V_;
    wconv_k<<<(nconv + 255) / 256, 256, 0, stream>>>(W1, W2, Wf, w1s, w2s, wft);
    net_k<<<256, 256, 0, stream>>>(index, targets, tok, pos, ln1g, ln1b, ln2g, ln2b,
                                   b1, b2, fng, fnb, bfv, w1s, w2s, wft, pred, partial);
    lossred_k<<<1, 256, 0, stream>>>(partial, lossp);
}

// Round 3
// 274.368 us; speedup vs baseline: 2.7777x; 2.4713x over previous
//
#include <hip/hip_runtime.h>

typedef __attribute__((ext_vector_type(4))) float f32x4;
typedef __attribute__((ext_vector_type(8))) short short8;
typedef unsigned short ushort_t;
typedef unsigned int uint_t;

#define R_  32768
#define E_  192
#define V_  96
#define L_  6
#define EPS_ 1e-5f

#define NCHUNK 24
#define NT 144              // L_ * NCHUNK
#define CH_BYTES 28672      // padded chunk stride: 12800 (w1) + 15360 (w2) + 512 pad
#define CH_US 14336
#define W2_OFF 12800        // byte offset of w2 part within a chunk
#define PP_F 1792           // floats per layer param block (= 7168 bytes)

__device__ __forceinline__ float bf2f(ushort_t u) {
    uint_t i = ((uint_t)u) << 16;
    return __builtin_bit_cast(float, i);
}
__device__ __forceinline__ ushort_t f2bf(float f) {
    uint_t i = __builtin_bit_cast(uint_t, f);
    uint_t r = (i + 0x7fffu + ((i >> 16) & 1u)) >> 16;   // RNE
    return (ushort_t)r;
}
__device__ __forceinline__ short8 pack8(const float* v) {
    uint4 u;
    u.x = (uint_t)f2bf(v[0]) | ((uint_t)f2bf(v[1]) << 16);
    u.y = (uint_t)f2bf(v[2]) | ((uint_t)f2bf(v[3]) << 16);
    u.z = (uint_t)f2bf(v[4]) | ((uint_t)f2bf(v[5]) << 16);
    u.w = (uint_t)f2bf(v[6]) | ((uint_t)f2bf(v[7]) << 16);
    return __builtin_bit_cast(short8, u);
}
__device__ __forceinline__ void unpack8(short8 s, float* v) {
    uint4 u = __builtin_bit_cast(uint4, s);
    v[0] = bf2f((ushort_t)u.x); v[1] = bf2f((ushort_t)(u.x >> 16));
    v[2] = bf2f((ushort_t)u.y); v[3] = bf2f((ushort_t)(u.y >> 16));
    v[4] = bf2f((ushort_t)u.z); v[5] = bf2f((ushort_t)(u.z >> 16));
    v[6] = bf2f((ushort_t)u.w); v[7] = bf2f((ushort_t)(u.w >> 16));
}
__device__ __forceinline__ void ldf8(const float* p, float* o) {
    float4 a = *(const float4*)p, b = *(const float4*)(p + 4);
    o[0] = a.x; o[1] = a.y; o[2] = a.z; o[3] = a.w;
    o[4] = b.x; o[5] = b.y; o[6] = b.z; o[7] = b.w;
}

// async global->LDS DMA, 16B per lane: LDS dest = wave-uniform base + lane*16,
// global src = per-lane address.
typedef __attribute__((address_space(1))) const uint_t as1_uint;
typedef __attribute__((address_space(3))) uint_t as3_uint;
__device__ __forceinline__ void glds16(const void* g, void* l) {
    __builtin_amdgcn_global_load_lds((as1_uint*)g, (as3_uint*)l, 16, 0, 0);
}
// each wave stages 7 KiB (7 x 1KiB wave-issues); 4 waves cover one 28 KiB chunk
__device__ __forceinline__ void stage7(const char* gchunk, char* lbuf, int w, int lane) {
    const char* g = gchunk + w * 7168 + lane * 16;
    char* l = lbuf + w * 7168;
#pragma unroll
    for (int i = 0; i < 7; ++i) glds16(g + i * 1024, l + i * 1024);
}
// single wave stages a 7 KiB param block
__device__ __forceinline__ void stagep(const char* gsrc, char* lbuf, int lane) {
    const char* g = gsrc + lane * 16;
#pragma unroll
    for (int i = 0; i < 7; ++i) glds16(g + i * 1024, lbuf + i * 1024);
}

// ---- C-layout pair (two 16-row tiles of the swapped-GEMM output) -> B-fragment ----
// D_t: lane(g=l>>4,c=l&15) holds out-row = t*16 + g*4 + r at col c (col = data row).
// Want: lane(g,c) holds out-row = 8g + j (j=0..7) at col c.
__device__ __forceinline__ void exch(f32x4 D0, f32x4 D1, int lane, float* v) {
    const int srcA = ((lane & 16) << 1) + (lane & 15);
    const int srcB = srcA + 16;
    const bool hi = (lane & 32) != 0;
#pragma unroll
    for (int r = 0; r < 4; ++r) {
        float a0 = __shfl(D0[r], srcA);
        float a1 = __shfl(D1[r], srcA);
        float b0 = __shfl(D0[r], srcB);
        float b1 = __shfl(D1[r], srcB);
        v[r]     = hi ? a1 : a0;
        v[4 + r] = hi ? b1 : b0;
    }
}

// ---- double LayerNorm on one register-fragment row set; params from LDS ----
// plds layout (floats): [0]g1 [192]b1 [384]g2 [576]b2 [768]bias1(768) [1536]bias2(192)
__device__ __forceinline__ void ln2_frags1(short8 (&xf)[6], const float* p, int lane) {
    const int g = lane >> 4;
    float v[48];
#pragma unroll
    for (int kc = 0; kc < 6; ++kc) unpack8(xf[kc], v + kc * 8);
    float s = 0.f, sq = 0.f;
#pragma unroll
    for (int j = 0; j < 48; ++j) { s += v[j]; sq += v[j] * v[j]; }
    s += __shfl_xor(s, 16); sq += __shfl_xor(sq, 16);
    s += __shfl_xor(s, 32); sq += __shfl_xor(sq, 32);
    float mu = s * (1.f / 192.f);
    float r1 = rsqrtf(sq * (1.f / 192.f) - mu * mu + EPS_);
#pragma unroll
    for (int kc = 0; kc < 6; ++kc) {
        float ga[8], ba[8];
        ldf8(p + kc * 32 + g * 8, ga);
        ldf8(p + 192 + kc * 32 + g * 8, ba);
#pragma unroll
        for (int j = 0; j < 8; ++j)
            v[kc * 8 + j] = (v[kc * 8 + j] - mu) * r1 * ga[j] + ba[j];
    }
    s = 0.f; sq = 0.f;
#pragma unroll
    for (int j = 0; j < 48; ++j) { s += v[j]; sq += v[j] * v[j]; }
    s += __shfl_xor(s, 16); sq += __shfl_xor(sq, 16);
    s += __shfl_xor(s, 32); sq += __shfl_xor(sq, 32);
    float mu2 = s * (1.f / 192.f);
    float r2 = rsqrtf(sq * (1.f / 192.f) - mu2 * mu2 + EPS_);
#pragma unroll
    for (int kc = 0; kc < 6; ++kc) {
        float ga[8], ba[8];
        ldf8(p + 384 + kc * 32 + g * 8, ga);
        ldf8(p + 576 + kc * 32 + g * 8, ba);
        float o[8];
#pragma unroll
        for (int j = 0; j < 8; ++j)
            o[j] = (v[kc * 8 + j] - mu2) * r2 * ga[j] + ba[j];
        xf[kc] = pack8(o);
    }
}

// ---- single LayerNorm, params from global ----
__device__ __forceinline__ void lnf_frags1(short8 (&xf)[6], const float* gg, const float* bb, int lane) {
    const int g = lane >> 4;
    float v[48];
#pragma unroll
    for (int kc = 0; kc < 6; ++kc) unpack8(xf[kc], v + kc * 8);
    float s = 0.f, sq = 0.f;
#pragma unroll
    for (int j = 0; j < 48; ++j) { s += v[j]; sq += v[j] * v[j]; }
    s += __shfl_xor(s, 16); sq += __shfl_xor(sq, 16);
    s += __shfl_xor(s, 32); sq += __shfl_xor(sq, 32);
    float mu = s * (1.f / 192.f);
    float r1 = rsqrtf(sq * (1.f / 192.f) - mu * mu + EPS_);
#pragma unroll
    for (int kc = 0; kc < 6; ++kc) {
        float ga[8], ba[8];
        ldf8(gg + kc * 32 + g * 8, ga);
        ldf8(bb + kc * 32 + g * 8, ba);
        float o[8];
#pragma unroll
        for (int j = 0; j < 8; ++j)
            o[j] = (v[kc * 8 + j] - mu) * r1 * ga[j] + ba[j];
        xf[kc] = pack8(o);
    }
}

// ---------------- weight/param convert to prelaid chunked layouts ----------------
__global__ void wconv_k(const float* __restrict__ W1, const float* __restrict__ W2,
                        const float* __restrict__ Wf,
                        const float* __restrict__ g1, const float* __restrict__ b1n,
                        const float* __restrict__ g2, const float* __restrict__ b2n,
                        const float* __restrict__ bb1, const float* __restrict__ bb2,
                        ushort_t* __restrict__ wch, ushort_t* __restrict__ wft,
                        float* __restrict__ pp)
{
    int i = blockIdx.x * 256 + threadIdx.x;
    const int NW = 884736;
    if (i < NW) {   // w1 part: chunk t, row fl (stride 200 us), elem e
        int e = i % 192; int i2 = i / 192;
        int fl = i2 % 32; int t = i2 / 32;
        int cc = t % 24; int l = t / 24;
        wch[(size_t)t * CH_US + fl * 200 + e] = f2bf(W1[((size_t)l * 192 + e) * 768 + cc * 32 + fl]);
        return;
    }
    i -= NW;
    if (i < NW) {   // w2 part: chunk t, row e (stride 40 us), elem fl
        int fl = i % 32; int i2 = i / 32;
        int e = i2 % 192; int t = i2 / 192;
        int cc = t % 24; int l = t / 24;
        wch[(size_t)t * CH_US + 6400 + e * 40 + fl] = f2bf(W2[((size_t)l * 768 + cc * 32 + fl) * 192 + e]);
        return;
    }
    i -= NW;
    if (i < 192 * 96) {
        int k = i / 96, v = i % 96;
        wft[(size_t)v * 192 + k] = f2bf(Wf[i]);   // [V][192] k-minor
        return;
    }
    i -= 192 * 96;
    if (i < L_ * PP_F) {
        int l = i / PP_F, j = i % PP_F;
        float val = 0.f;
        if      (j < 192)  val = g1 [l * 192 + j];
        else if (j < 384)  val = b1n[l * 192 + j - 192];
        else if (j < 576)  val = g2 [l * 192 + j - 384];
        else if (j < 768)  val = b2n[l * 192 + j - 576];
        else if (j < 1536) val = bb1[l * 768 + j - 768];
        else if (j < 1728) val = bb2[l * 192 + j - 1536];
        pp[(size_t)l * PP_F + j] = val;
    }
}

// ---------------- the whole network, one kernel, 64 rows/block ----------------
__global__ __launch_bounds__(256, 2) void net_k(
    const int* __restrict__ idxp, const int* __restrict__ tgp,
    const float* __restrict__ tok, const float* __restrict__ pos,
    const float* __restrict__ fng, const float* __restrict__ fnb,
    const float* __restrict__ bfb,
    const ushort_t* __restrict__ wch, const ushort_t* __restrict__ wft,
    const float* __restrict__ pp,
    float* __restrict__ pred, float* __restrict__ partial)
{
    __shared__ __align__(16) ushort_t wlds[2][CH_US];
    __shared__ __align__(16) float plds[2][PP_F];
    __shared__ float lsred[4];

    const int tid = threadIdx.x, lane = tid & 63, w = tid >> 6;
    const int c = lane & 15, g = lane >> 4;
    const int row = blockIdx.x * 64 + w * 16 + c;

    // prologue staging: weight chunk 0 (all waves) + layer-0 params (wave 0)
    stage7((const char*)wch, (char*)&wlds[0][0], w, lane);
    if (w == 0) stagep((const char*)pp, (char*)&plds[0][0], lane);

    // embedding -> x B-fragments: lane(g,c) holds row `c`, k = kc*32 + g*8 + j
    short8 xf[6];
    {
        int id = idxp[row];
        int tt = row & 127;
#pragma unroll
        for (int kc = 0; kc < 6; ++kc) {
            float a[8], b[8], v[8];
            ldf8(tok + (size_t)id * 192 + kc * 32 + g * 8, a);
            ldf8(pos + (size_t)tt * 192 + kc * 32 + g * 8, b);
#pragma unroll
            for (int j = 0; j < 8; ++j) v[j] = a[j] + b[j];
            xf[kc] = pack8(v);
        }
    }
    __syncthreads();

    int cur = 0, pcur = 0;
#pragma unroll 1
    for (int l = 0; l < L_; ++l) {
        ln2_frags1(xf, &plds[pcur][0], lane);    // n2 = LN2(LN1(x)) in-register

        f32x4 axT[12] = {};                       // x^T accumulator (E rows x our cols)
#pragma unroll 1
        for (int cc = 0; cc < NCHUNK; ++cc) {
            const int t = l * NCHUNK + cc;
            // issue next-chunk DMA first: latency hides under this chunk's compute
            if (t + 1 < NT)
                stage7((const char*)wch + (size_t)(t + 1) * CH_BYTES, (char*)&wlds[cur ^ 1][0], w, lane);
            if (cc == NCHUNK - 1 && l + 1 < L_ && w == 0)
                stagep((const char*)pp + (size_t)(l + 1) * (PP_F * 4), (char*)&plds[pcur ^ 1][0], lane);

            const char* wb = (const char*)&wlds[cur][0];
            uint4 wa[12], w2r[12];
#pragma unroll
            for (int kc = 0; kc < 6; ++kc)
#pragma unroll
                for (int fi = 0; fi < 2; ++fi)
                    wa[kc * 2 + fi] = *(const uint4*)(wb + (fi * 16 + c) * 400 + kc * 64 + g * 16);
#pragma unroll
            for (int et = 0; et < 12; ++et)
                w2r[et] = *(const uint4*)(wb + W2_OFF + (et * 16 + c) * 80 + g * 16);

            // gemm1 (swapped): hT[f_loc][our rows] = W1chunk x x
            f32x4 ah0 = {}, ah1 = {};
            __builtin_amdgcn_s_setprio(1);
#pragma unroll
            for (int kc = 0; kc < 6; ++kc) {
                ah0 = __builtin_amdgcn_mfma_f32_16x16x32_bf16(__builtin_bit_cast(short8, wa[kc * 2]),     xf[kc], ah0, 0, 0, 0);
                ah1 = __builtin_amdgcn_mfma_f32_16x16x32_bf16(__builtin_bit_cast(short8, wa[kc * 2 + 1]), xf[kc], ah1, 0, 0, 0);
            }
            __builtin_amdgcn_s_setprio(0);

            // hT -> h B-fragment (+bias1, relu)
            float v[8], bv[8];
            exch(ah0, ah1, lane, v);
            ldf8(&plds[pcur][768 + cc * 32 + g * 8], bv);
#pragma unroll
            for (int j = 0; j < 8; ++j) {
                float y = v[j] + bv[j];
                v[j] = y > 0.f ? y : 0.f;
            }
            short8 hb = pack8(v);

            // gemm2 (swapped): xT[e][our rows] += W2chunk x h
            __builtin_amdgcn_s_setprio(1);
#pragma unroll
            for (int et = 0; et < 12; ++et)
                axT[et] = __builtin_amdgcn_mfma_f32_16x16x32_bf16(__builtin_bit_cast(short8, w2r[et]), hb, axT[et], 0, 0, 0);
            __builtin_amdgcn_s_setprio(0);

            __syncthreads();     // drains glds vmcnt, flips double buffer
            cur ^= 1;
        }

        // layer end: xT (+bias2) -> new x B-fragments
#pragma unroll
        for (int e = 0; e < 6; ++e) {
            float v[8], bv[8];
            exch(axT[2 * e], axT[2 * e + 1], lane, v);
            ldf8(&plds[pcur][1536 + e * 32 + g * 8], bv);
#pragma unroll
            for (int j = 0; j < 8; ++j) v[j] += bv[j];
            xf[e] = pack8(v);
        }
        pcur ^= 1;
    }

    // ---- final LN + head ----
    lnf_frags1(xf, fng, fnb, lane);
    f32x4 av[6] = {};
    __builtin_amdgcn_s_setprio(1);
#pragma unroll
    for (int kc = 0; kc < 6; ++kc)
#pragma unroll
        for (int vt = 0; vt < 6; ++vt) {
            short8 wf = *(const short8*)(wft + (size_t)(vt * 16 + c) * 192 + kc * 32 + g * 8);
            av[vt] = __builtin_amdgcn_mfma_f32_16x16x32_bf16(wf, xf[kc], av[vt], 0, 0, 0);
        }
    __builtin_amdgcn_s_setprio(0);

    float vv[6][4];
#pragma unroll
    for (int vt = 0; vt < 6; ++vt) {
        float4 bb = *(const float4*)(bfb + vt * 16 + g * 4);
        vv[vt][0] = av[vt][0] + bb.x;
        vv[vt][1] = av[vt][1] + bb.y;
        vv[vt][2] = av[vt][2] + bb.z;
        vv[vt][3] = av[vt][3] + bb.w;
    }
    float mx = -1e30f;
#pragma unroll
    for (int vt = 0; vt < 6; ++vt)
#pragma unroll
        for (int r = 0; r < 4; ++r) mx = fmaxf(mx, vv[vt][r]);
    mx = fmaxf(mx, __shfl_xor(mx, 16));
    mx = fmaxf(mx, __shfl_xor(mx, 32));
    float se = 0.f;
#pragma unroll
    for (int vt = 0; vt < 6; ++vt)
#pragma unroll
        for (int r = 0; r < 4; ++r) se += expf(vv[vt][r] - mx);
    se += __shfl_xor(se, 16);
    se += __shfl_xor(se, 32);
    float lse = logf(se) + mx;
    int tgt = tgp[row];
    float lsum = 0.f;
#pragma unroll
    for (int vt = 0; vt < 6; ++vt)
#pragma unroll
        for (int r = 0; r < 4; ++r)
            if (tgt == vt * 16 + g * 4 + r) lsum += lse - vv[vt][r];
#pragma unroll
    for (int vt = 0; vt < 6; ++vt) {
        float4 o;
        o.x = vv[vt][0]; o.y = vv[vt][1]; o.z = vv[vt][2]; o.w = vv[vt][3];
        *(float4*)(pred + (size_t)row * 96 + vt * 16 + g * 4) = o;
    }
#pragma unroll
    for (int m = 1; m < 64; m <<= 1) lsum += __shfl_xor(lsum, m);
    if (lane == 0) lsred[w] = lsum;
    __syncthreads();
    if (tid == 0) partial[blockIdx.x] = lsred[0] + lsred[1] + lsred[2] + lsred[3];
}

__global__ void lossred_k(const float* __restrict__ partial, float* __restrict__ out)
{
    __shared__ double sd[256];
    int t = threadIdx.x;
    sd[t] = (double)partial[t] + (double)partial[t + 256];
    __syncthreads();
    for (int s = 128; s > 0; s >>= 1) {
        if (t < s) sd[t] += sd[t + s];
        __syncthreads();
    }
    if (t == 0) out[0] = (float)(sd[0] / (double)R_);
}

extern "C" void kernel_launch(void* const* d_in, const int* in_sizes, int n_in,
                              void* d_out, int out_size, void* d_ws, size_t ws_size,
                              hipStream_t stream)
{
    (void)in_sizes; (void)n_in; (void)out_size; (void)ws_size;
    const int*   index   = (const int*)  d_in[0];
    const int*   targets = (const int*)  d_in[1];
    const float* tok     = (const float*)d_in[2];
    const float* pos     = (const float*)d_in[3];
    const float* ln1g    = (const float*)d_in[4];
    const float* ln1b    = (const float*)d_in[5];
    const float* ln2g    = (const float*)d_in[6];
    const float* ln2b    = (const float*)d_in[7];
    // d_in[8..10] = Wq/Wk/Wv: dead in the reference forward
    const float* W1      = (const float*)d_in[11];
    const float* b1      = (const float*)d_in[12];
    const float* W2      = (const float*)d_in[13];
    const float* b2      = (const float*)d_in[14];
    const float* fng     = (const float*)d_in[15];
    const float* fnb     = (const float*)d_in[16];
    const float* Wf      = (const float*)d_in[17];
    const float* bfv     = (const float*)d_in[18];

    ushort_t* wch = (ushort_t*)d_ws;                        // [144][14336] us (28672B chunks)
    ushort_t* wft = wch + (size_t)NT * CH_US;               // [96][192]
    float* pp     = (float*)(wft + 192 * 96);               // [6][1792] f32 (16B-aligned)
    float* partial = pp + (size_t)L_ * PP_F;                // [512]
    float* pred  = (float*)d_out;
    float* lossp = pred + (size_t)R_ * V_;

    const int nconv = 2 * 884736 + 192 * 96 + L_ * PP_F;    // 1798656 = 7026*256
    wconv_k<<<nconv / 256, 256, 0, stream>>>(W1, W2, Wf, ln1g, ln1b, ln2g, ln2b,
                                             b1, b2, wch, wft, pp);
    net_k<<<512, 256, 0, stream>>>(index, targets, tok, pos, fng, fnb, bfv,
                                   wch, wft, pp, pred, partial);
    lossred_k<<<1, 256, 0, stream>>>(partial, lossp);
}

// Round 4
// 202.832 us; speedup vs baseline: 3.7574x; 1.3527x over previous
//
#include <hip/hip_runtime.h>

typedef __attribute__((ext_vector_type(4))) float f32x4;
typedef __attribute__((ext_vector_type(8))) short short8;
typedef unsigned short ushort_t;
typedef unsigned int uint_t;

#define R_  32768
#define E_  192
#define V_  96
#define L_  6
#define EPS_ 1e-5f

#define NCHUNK 24
#define NT 144              // L_ * NCHUNK
#define CH_US 12288         // ushorts per chunk: 12 w1 frags + 12 w2 frags, 512 us each
#define CH_BYTES 24576
#define W2_OFF 12288        // byte offset of w2 fragment region within a chunk
#define PP_F 1792           // floats per layer param block (= 7168 bytes)

__device__ __forceinline__ ushort_t f2bf(float f) {
    uint_t i = __builtin_bit_cast(uint_t, f);
    uint_t r = (i + 0x7fffu + ((i >> 16) & 1u)) >> 16;   // RNE
    return (ushort_t)r;
}
// packed f32 pair -> bf16x2 dword (RNE), single HW instr
__device__ __forceinline__ uint_t cvtpk(float a, float b) {
    uint_t r;
    asm("v_cvt_pk_bf16_f32 %0, %1, %2" : "=v"(r) : "v"(a), "v"(b));
    return r;
}

// async global->LDS DMA, 16B per lane: LDS dest = wave-uniform base + lane*16
typedef __attribute__((address_space(1))) const uint_t as1_uint;
typedef __attribute__((address_space(3))) uint_t as3_uint;
__device__ __forceinline__ void glds16(const void* g, void* l) {
    __builtin_amdgcn_global_load_lds((as1_uint*)g, (as3_uint*)l, 16, 0, 0);
}
// each wave stages 6 KiB; 4 waves cover one 24 KiB chunk
__device__ __forceinline__ void stage6(const char* gchunk, char* lbuf, int w, int lane) {
    const char* g = gchunk + w * 6144 + lane * 16;
    char* l = lbuf + w * 6144;
#pragma unroll
    for (int i = 0; i < 6; ++i) glds16(g + i * 1024, l + i * 1024);
}
// single wave stages a 7 KiB param block
__device__ __forceinline__ void stagep(const char* gsrc, char* lbuf, int lane) {
    const char* g = gsrc + lane * 16;
#pragma unroll
    for (int i = 0; i < 7; ++i) glds16(g + i * 1024, lbuf + i * 1024);
}

// ---- LayerNorm on D-layout register state ----
// lane(g,c) holds x[e = et*16 + g*4 + r][row=c] in a[et][r]; reduce across g (xor 16,32)
__device__ __forceinline__ void lnD(f32x4 (&a)[12], const float* gp, const float* bp, int g) {
    float s = 0.f, sq = 0.f;
#pragma unroll
    for (int et = 0; et < 12; ++et)
#pragma unroll
        for (int r = 0; r < 4; ++r) { float x = a[et][r]; s += x; sq += x * x; }
    s += __shfl_xor(s, 16); sq += __shfl_xor(sq, 16);
    s += __shfl_xor(s, 32); sq += __shfl_xor(sq, 32);
    float mu = s * (1.f / 192.f);
    float ri = rsqrtf(sq * (1.f / 192.f) - mu * mu + EPS_);
#pragma unroll
    for (int et = 0; et < 12; ++et) {
        float4 gg = *(const float4*)(gp + et * 16 + g * 4);
        float4 bb = *(const float4*)(bp + et * 16 + g * 4);
        a[et][0] = (a[et][0] - mu) * ri * gg.x + bb.x;
        a[et][1] = (a[et][1] - mu) * ri * gg.y + bb.y;
        a[et][2] = (a[et][2] - mu) * ri * gg.z + bb.z;
        a[et][3] = (a[et][3] - mu) * ri * gg.w + bb.w;
    }
}

// ---- pack D-layout f32 state to bf16 and exchange into B-fragments ----
// dst xf[kc] dword d = x[e = kc*32 + 8g + 2d (,+1)][row c]
// src: lane (2(g&1)+(d>>1))*16 + c, tile et = 2kc+(g>>1), packed slot d&1
__device__ __forceinline__ void packex(const f32x4 (&a)[12], int lane, short8 (&xf)[6]) {
    uint_t pk[12][2];
#pragma unroll
    for (int et = 0; et < 12; ++et) {
        pk[et][0] = cvtpk(a[et][0], a[et][1]);
        pk[et][1] = cvtpk(a[et][2], a[et][3]);
    }
    const bool hi = (lane & 32) != 0;
    const int base = ((lane & 16) << 1) + (lane & 15);
#pragma unroll
    for (int kc = 0; kc < 6; ++kc) {
        uint_t dw[4];
#pragma unroll
        for (int d = 0; d < 4; ++d) {
            int src = base + (d >> 1) * 16;
            uint_t A = (uint_t)__shfl((int)pk[2 * kc][d & 1], src);
            uint_t B = (uint_t)__shfl((int)pk[2 * kc + 1][d & 1], src);
            dw[d] = hi ? B : A;
        }
        uint4 q; q.x = dw[0]; q.y = dw[1]; q.z = dw[2]; q.w = dw[3];
        xf[kc] = __builtin_bit_cast(short8, q);
    }
}

// ---------------- weight/param convert: fragment-ordered chunks ----------------
__global__ void wconv_k(const float* __restrict__ W1, const float* __restrict__ W2,
                        const float* __restrict__ Wf,
                        const float* __restrict__ g1, const float* __restrict__ b1n,
                        const float* __restrict__ g2, const float* __restrict__ b2n,
                        const float* __restrict__ bb1, const float* __restrict__ bb2,
                        ushort_t* __restrict__ wch, ushort_t* __restrict__ wfr,
                        float* __restrict__ pp)
{
    int i = blockIdx.x * 256 + threadIdx.x;
    const int NW = 884736;
    if (i < NW) {   // w1 fragments: chunk t, block (kc*2+fi), lane li, elem j
        int t = i / 6144, wc = i % 6144;
        int blk = wc >> 9, li = (wc >> 3) & 63, j = wc & 7;
        int kc = blk >> 1, fi = blk & 1, g = li >> 4, c = li & 15;
        int cc = t % 24, lyr = t / 24;
        int e = kc * 32 + g * 8 + j, f = cc * 32 + fi * 16 + c;
        wch[(size_t)t * CH_US + wc] = f2bf(W1[((size_t)lyr * 192 + e) * 768 + f]);
        return;
    }
    i -= NW;
    if (i < NW) {   // w2 fragments: block et, lane li, elem j
        int t = i / 6144, wc = i % 6144;
        int et = wc >> 9, li = (wc >> 3) & 63, j = wc & 7;
        int g = li >> 4, c = li & 15;
        int cc = t % 24, lyr = t / 24;
        wch[(size_t)t * CH_US + 6144 + wc] =
            f2bf(W2[((size_t)lyr * 768 + cc * 32 + g * 8 + j) * 192 + et * 16 + c]);
        return;
    }
    i -= NW;
    if (i < 36 * 512) {   // head fragments: block (kc*6+vt)
        int blk = i >> 9, li = (i >> 3) & 63, j = i & 7;
        int kc = blk / 6, vt = blk % 6, g = li >> 4, c = li & 15;
        wfr[i] = f2bf(Wf[((size_t)kc * 32 + g * 8 + j) * 96 + vt * 16 + c]);
        return;
    }
    i -= 36 * 512;
    if (i < L_ * PP_F) {
        int l = i / PP_F, j = i % PP_F;
        float val = 0.f;
        if      (j < 192)  val = g1 [l * 192 + j];
        else if (j < 384)  val = b1n[l * 192 + j - 192];
        else if (j < 576)  val = g2 [l * 192 + j - 384];
        else if (j < 768)  val = b2n[l * 192 + j - 576];
        else if (j < 1536) val = bb1[l * 768 + j - 768];
        else if (j < 1728) val = bb2[l * 192 + j - 1536];
        pp[(size_t)l * PP_F + j] = val;
    }
}

// ---------------- the whole network, one kernel, 64 rows/block ----------------
__global__ __launch_bounds__(256, 2) void net_k(
    const int* __restrict__ idxp, const int* __restrict__ tgp,
    const float* __restrict__ tok, const float* __restrict__ pos,
    const float* __restrict__ fng, const float* __restrict__ fnb,
    const float* __restrict__ bfb,
    const ushort_t* __restrict__ wch, const ushort_t* __restrict__ wfr,
    const float* __restrict__ pp,
    float* __restrict__ pred, float* __restrict__ partial)
{
    __shared__ __align__(16) ushort_t wlds[2][CH_US];
    __shared__ __align__(16) float plds[2][PP_F];
    __shared__ float lsred[4];

    const int tid = threadIdx.x, lane = tid & 63, w = tid >> 6;
    const int c = lane & 15, g = lane >> 4;
    const int myrow = blockIdx.x * 64 + w * 16 + c;

    // prologue staging: weight chunk 0 (all waves) + layer-0 params (wave 0)
    stage6((const char*)wch, (char*)&wlds[0][0], w, lane);
    if (w == 0) stagep((const char*)pp, (char*)&plds[0][0], lane);

    // embedding directly in D-layout: lane(g,c) holds x[e=et*16+g*4+r][row c]
    f32x4 axT[12];
    {
        int id = idxp[myrow];
        int tt = myrow & 127;
#pragma unroll
        for (int et = 0; et < 12; ++et) {
            float4 a = *(const float4*)(tok + (size_t)id * 192 + et * 16 + g * 4);
            float4 b = *(const float4*)(pos + (size_t)tt * 192 + et * 16 + g * 4);
            axT[et][0] = a.x + b.x; axT[et][1] = a.y + b.y;
            axT[et][2] = a.z + b.z; axT[et][3] = a.w + b.w;
        }
    }
    __syncthreads();

    const bool hi = (lane & 32) != 0;
    const int xbase = ((lane & 16) << 1) + (lane & 15);

    int cur = 0, pcur = 0;
#pragma unroll 1
    for (int l = 0; l < L_; ++l) {
        // n2 = LN2(LN1(x)) on D-layout state, then pack+exchange into B-frags
        lnD(axT, &plds[pcur][0],   &plds[pcur][192], g);
        lnD(axT, &plds[pcur][384], &plds[pcur][576], g);
        short8 xf[6];
        packex(axT, lane, xf);
#pragma unroll
        for (int et = 0; et < 12; ++et) { axT[et][0] = 0.f; axT[et][1] = 0.f; axT[et][2] = 0.f; axT[et][3] = 0.f; }

#pragma unroll 1
        for (int cc = 0; cc < NCHUNK; ++cc) {
            const int t = l * NCHUNK + cc;
            if (t + 1 < NT)
                stage6((const char*)wch + (size_t)(t + 1) * CH_BYTES, (char*)&wlds[cur ^ 1][0], w, lane);
            if (cc == NCHUNK - 1 && l + 1 < L_ && w == 0)
                stagep((const char*)pp + (size_t)(l + 1) * (PP_F * 4), (char*)&plds[pcur ^ 1][0], lane);

            const char* wb = (const char*)&wlds[cur][0] + lane * 16;

            // gemm1 (swapped): hT = W1chunk x x ; fragments linear, conflict-free
            f32x4 ah0 = {}, ah1 = {};
            __builtin_amdgcn_s_setprio(1);
#pragma unroll
            for (int kc = 0; kc < 6; ++kc) {
                uint4 wa0 = *(const uint4*)(wb + (kc * 2) * 1024);
                uint4 wa1 = *(const uint4*)(wb + (kc * 2 + 1) * 1024);
                ah0 = __builtin_amdgcn_mfma_f32_16x16x32_bf16(__builtin_bit_cast(short8, wa0), xf[kc], ah0, 0, 0, 0);
                ah1 = __builtin_amdgcn_mfma_f32_16x16x32_bf16(__builtin_bit_cast(short8, wa1), xf[kc], ah1, 0, 0, 0);
            }
            __builtin_amdgcn_s_setprio(0);

            // bias1 + relu in D-layout, pack, then exchange packed dwords -> hb
            float4 b1a = *(const float4*)(&plds[pcur][768 + cc * 32 + g * 4]);
            float4 b1b = *(const float4*)(&plds[pcur][768 + cc * 32 + 16 + g * 4]);
            float y00 = fmaxf(ah0[0] + b1a.x, 0.f), y01 = fmaxf(ah0[1] + b1a.y, 0.f);
            float y02 = fmaxf(ah0[2] + b1a.z, 0.f), y03 = fmaxf(ah0[3] + b1a.w, 0.f);
            float y10 = fmaxf(ah1[0] + b1b.x, 0.f), y11 = fmaxf(ah1[1] + b1b.y, 0.f);
            float y12 = fmaxf(ah1[2] + b1b.z, 0.f), y13 = fmaxf(ah1[3] + b1b.w, 0.f);
            uint_t pA0 = cvtpk(y00, y01), pA1 = cvtpk(y02, y03);
            uint_t pB0 = cvtpk(y10, y11), pB1 = cvtpk(y12, y13);
            uint_t dw[4];
#pragma unroll
            for (int d = 0; d < 4; ++d) {
                int src = xbase + (d >> 1) * 16;
                uint_t A = (uint_t)__shfl((int)((d & 1) ? pA1 : pA0), src);
                uint_t B = (uint_t)__shfl((int)((d & 1) ? pB1 : pB0), src);
                dw[d] = hi ? B : A;
            }
            uint4 hq; hq.x = dw[0]; hq.y = dw[1]; hq.z = dw[2]; hq.w = dw[3];
            short8 hb = __builtin_bit_cast(short8, hq);

            // gemm2 (swapped): xT += W2chunk x h
            __builtin_amdgcn_s_setprio(1);
#pragma unroll
            for (int et = 0; et < 12; ++et) {
                uint4 wr = *(const uint4*)(wb + W2_OFF + et * 1024);
                axT[et] = __builtin_amdgcn_mfma_f32_16x16x32_bf16(__builtin_bit_cast(short8, wr), hb, axT[et], 0, 0, 0);
            }
            __builtin_amdgcn_s_setprio(0);

            __syncthreads();     // drains glds vmcnt, flips double buffer
            cur ^= 1;
        }

        // + bias2 (still D-layout)
#pragma unroll
        for (int et = 0; et < 12; ++et) {
            float4 bb = *(const float4*)(&plds[pcur][1536 + et * 16 + g * 4]);
            axT[et][0] += bb.x; axT[et][1] += bb.y; axT[et][2] += bb.z; axT[et][3] += bb.w;
        }
        pcur ^= 1;
    }

    // ---- final LN + head ----
    lnD(axT, fng, fnb, g);
    short8 xf[6];
    packex(axT, lane, xf);
    f32x4 av[6] = {};
    __builtin_amdgcn_s_setprio(1);
#pragma unroll
    for (int kc = 0; kc < 6; ++kc)
#pragma unroll
        for (int vt = 0; vt < 6; ++vt) {
            short8 wf = *(const short8*)(wfr + (size_t)(kc * 6 + vt) * 512 + lane * 8);
            av[vt] = __builtin_amdgcn_mfma_f32_16x16x32_bf16(wf, xf[kc], av[vt], 0, 0, 0);
        }
    __builtin_amdgcn_s_setprio(0);

    float vv[6][4];
#pragma unroll
    for (int vt = 0; vt < 6; ++vt) {
        float4 bb = *(const float4*)(bfb + vt * 16 + g * 4);
        vv[vt][0] = av[vt][0] + bb.x;
        vv[vt][1] = av[vt][1] + bb.y;
        vv[vt][2] = av[vt][2] + bb.z;
        vv[vt][3] = av[vt][3] + bb.w;
    }
    float mx = -1e30f;
#pragma unroll
    for (int vt = 0; vt < 6; ++vt)
#pragma unroll
        for (int r = 0; r < 4; ++r) mx = fmaxf(mx, vv[vt][r]);
    mx = fmaxf(mx, __shfl_xor(mx, 16));
    mx = fmaxf(mx, __shfl_xor(mx, 32));
    float se = 0.f;
#pragma unroll
    for (int vt = 0; vt < 6; ++vt)
#pragma unroll
        for (int r = 0; r < 4; ++r) se += expf(vv[vt][r] - mx);
    se += __shfl_xor(se, 16);
    se += __shfl_xor(se, 32);
    float lse = logf(se) + mx;
    int tgt = tgp[myrow];
    float lsum = 0.f;
#pragma unroll
    for (int vt = 0; vt < 6; ++vt)
#pragma unroll
        for (int r = 0; r < 4; ++r)
            if (tgt == vt * 16 + g * 4 + r) lsum += lse - vv[vt][r];
#pragma unroll
    for (int vt = 0; vt < 6; ++vt) {
        float4 o;
        o.x = vv[vt][0]; o.y = vv[vt][1]; o.z = vv[vt][2]; o.w = vv[vt][3];
        *(float4*)(pred + (size_t)myrow * 96 + vt * 16 + g * 4) = o;
    }
#pragma unroll
    for (int m = 1; m < 64; m <<= 1) lsum += __shfl_xor(lsum, m);
    if (lane == 0) lsred[w] = lsum;
    __syncthreads();
    if (tid == 0) partial[blockIdx.x] = lsred[0] + lsred[1] + lsred[2] + lsred[3];
}

__global__ void lossred_k(const float* __restrict__ partial, float* __restrict__ out)
{
    __shared__ double sd[256];
    int t = threadIdx.x;
    sd[t] = (double)partial[t] + (double)partial[t + 256];
    __syncthreads();
    for (int s = 128; s > 0; s >>= 1) {
        if (t < s) sd[t] += sd[t + s];
        __syncthreads();
    }
    if (t == 0) out[0] = (float)(sd[0] / (double)R_);
}

extern "C" void kernel_launch(void* const* d_in, const int* in_sizes, int n_in,
                              void* d_out, int out_size, void* d_ws, size_t ws_size,
                              hipStream_t stream)
{
    (void)in_sizes; (void)n_in; (void)out_size; (void)ws_size;
    const int*   index   = (const int*)  d_in[0];
    const int*   targets = (const int*)  d_in[1];
    const float* tok     = (const float*)d_in[2];
    const float* pos     = (const float*)d_in[3];
    const float* ln1g    = (const float*)d_in[4];
    const float* ln1b    = (const float*)d_in[5];
    const float* ln2g    = (const float*)d_in[6];
    const float* ln2b    = (const float*)d_in[7];
    // d_in[8..10] = Wq/Wk/Wv: dead in the reference forward
    const float* W1      = (const float*)d_in[11];
    const float* b1      = (const float*)d_in[12];
    const float* W2      = (const float*)d_in[13];
    const float* b2      = (const float*)d_in[14];
    const float* fng     = (const float*)d_in[15];
    const float* fnb     = (const float*)d_in[16];
    const float* Wf      = (const float*)d_in[17];
    const float* bfv     = (const float*)d_in[18];

    ushort_t* wch = (ushort_t*)d_ws;                        // [144][12288] us (24576B chunks)
    ushort_t* wfr = wch + (size_t)NT * CH_US;               // [36][512] head fragments
    float* pp     = (float*)(wfr + 36 * 512);               // [6][1792] f32 (16B-aligned)
    float* partial = pp + (size_t)L_ * PP_F;                // [512]
    float* pred  = (float*)d_out;
    float* lossp = pred + (size_t)R_ * V_;

    const int nconv = 2 * 884736 + 36 * 512 + L_ * PP_F;    // 1798656 = 7026*256
    wconv_k<<<nconv / 256, 256, 0, stream>>>(W1, W2, Wf, ln1g, ln1b, ln2g, ln2b,
                                             b1, b2, wch, wfr, pp);
    net_k<<<512, 256, 0, stream>>>(index, targets, tok, pos, fng, fnb, bfv,
                                   wch, wfr, pp, pred, partial);
    lossred_k<<<1, 256, 0, stream>>>(partial, lossp);
}